// Round 8
// baseline (694.728 us; speedup 1.0000x reference)
//
#include <hip/hip_runtime.h>

typedef __attribute__((ext_vector_type(8))) __bf16 bf16x8;
typedef __attribute__((ext_vector_type(4))) float f32x4;

__device__ __forceinline__ bf16x8 cvt8(f32x4 a, f32x4 b) {
    bf16x8 v;
    v[0] = (__bf16)a.x; v[1] = (__bf16)a.y; v[2] = (__bf16)a.z; v[3] = (__bf16)a.w;
    v[4] = (__bf16)b.x; v[5] = (__bf16)b.y; v[6] = (__bf16)b.z; v[7] = (__bf16)b.w;
    return v;
}

// ---------------------------------------------------------------------------
// Kernel 0: zero 512KB accumulator + build graph offsets from sorted batch.
// ---------------------------------------------------------------------------
__global__ void prep(const int* __restrict__ batch, int nN,
                     float* __restrict__ sums, int* __restrict__ off)
{
    const int i = blockIdx.x * blockDim.x + threadIdx.x;
    const int stride = gridDim.x * blockDim.x;
    for (int t = i; t < 1024 * 128; t += stride) sums[t] = 0.f;
    for (int t = i; t < nN; t += stride) {
        const int b  = batch[t];
        const int bp = (t == 0) ? -1 : batch[t - 1];
        for (int g = bp + 1; g <= b; ++g) off[g] = t;
        if (t == nN - 1) {
            for (int g = b + 1; g <= 1024; ++g) off[g] = nN;
        }
    }
}

// ---------------------------------------------------------------------------
// Kernel 1: TRANSPOSED decomposition. Each wave owns 16 nodes per window and
// ALL 256 output features. MFMA computes D = W (A-operand, LDS) x x^T
// (B-operand, registers direct from global): D[col=node(l15), row=feature].
// Softmax over features is in-lane (+2 shfl). Gating in-lane. Per-lane
// per-graph accumulators; cross-lane reduce + atomics only at graph
// boundaries. NO barriers in the main loop.
// ---------------------------------------------------------------------------
__global__ __launch_bounds__(512, 4) void gnn_main(
    const float* __restrict__ x, const int* __restrict__ batch,
    const float* __restrict__ Wlin, const float* __restrict__ blin,
    const float* __restrict__ Wgate, const float* __restrict__ bgate,
    float* __restrict__ sums, int nN, int PW)
{
    __shared__ __bf16 WL[128 * 128];   // 32 KB, XOR-swizzled bf16
    __shared__ __bf16 WG[128 * 128];   // 32 KB

    const int tid  = threadIdx.x;
    const int lane = tid & 63;
    const int w    = tid >> 6;    // wave 0..7
    const int l15  = lane & 15;
    const int lg   = lane >> 4;   // 0..3

    // ---- one-time stage of both W matrices into LDS (bf16, swizzled)
    for (int idx = tid; idx < 4096; idx += 512) {
        const int c  = idx >> 4;     // 0..255 (0-127 lin, 128-255 gate)
        const int kg = idx & 15;
        const int row = c & 127;
        const float* src = (c < 128 ? Wlin + (size_t)row * 128
                                    : Wgate + (size_t)row * 128) + kg * 8;
        f32x4 u0 = *(const f32x4*)src;
        f32x4 u1 = *(const f32x4*)(src + 4);
        __bf16* dstm = (c < 128) ? WL : WG;
        const int byte = (row * 256 + kg * 16) ^ ((row & 7) << 4);
        *(bf16x8*)((char*)dstm + byte) = cvt8(u0, u1);
    }
    __syncthreads();   // the only barrier

    // ---- this wave's contiguous node range
    const int wid = blockIdx.x * 8 + w;
    const long r0l = (long)wid * PW;
    if (r0l >= nN) return;
    const int R0 = (int)r0l;
    const int R1 = min(R0 + PW, nN);

    f32x4 racc[8];
#pragma unroll
    for (int j = 0; j < 8; ++j) racc[j] = (f32x4)0.f;
    int gcur = batch[R0];

    auto flush = [&](int g) {
#pragma unroll
        for (int j = 0; j < 8; ++j) {
            f32x4 v = racc[j];
#pragma unroll
            for (int d = 1; d <= 8; d <<= 1) {
                v.x += __shfl_xor(v.x, d);
                v.y += __shfl_xor(v.y, d);
                v.z += __shfl_xor(v.z, d);
                v.w += __shfl_xor(v.w, d);
            }
            if (l15 == 0) {
                float* dst = sums + (size_t)g * 128 + j * 16 + lg * 4;
                atomicAdd(dst + 0, v.x);
                atomicAdd(dst + 1, v.y);
                atomicAdd(dst + 2, v.z);
                atomicAdd(dst + 3, v.w);
            }
            racc[j] = (f32x4)0.f;
        }
    };

    for (int base = R0; base < R1; base += 16) {
        const int nvalid = min(16, nN - base);
        const int node = base + (l15 < nvalid ? l15 : nvalid - 1);

        // ---- x B-fragments direct from global (32B/lane/kk), f32->bf16
        bf16x8 xf[4];
        const float* xr = x + (size_t)node * 128 + lg * 8;
#pragma unroll
        for (int kk = 0; kk < 4; ++kk)
            xf[kk] = cvt8(*(const f32x4*)(xr + kk * 32),
                          *(const f32x4*)(xr + kk * 32 + 4));

        // ---- gate pass: aG[j] = Wgate-block-j x x^T
        f32x4 aG[8];
#pragma unroll
        for (int j = 0; j < 8; ++j) aG[j] = (f32x4)0.f;
#pragma unroll
        for (int kk = 0; kk < 4; ++kk) {
#pragma unroll
            for (int j = 0; j < 8; ++j) {
                const int byte = ((16 * j + l15) * 256 + kk * 64 + lg * 16)
                                 ^ ((l15 & 7) << 4);
                bf16x8 wf = *(const bf16x8*)((const char*)WG + byte);
                aG[j] = __builtin_amdgcn_mfma_f32_16x16x32_bf16(wf, xf[kk], aG[j], 0, 0, 0);
            }
        }

        // ---- softmax over features: in-lane 32-sum + 2 shuffles
        float den = 0.f;
#pragma unroll
        for (int j = 0; j < 8; ++j) {
            f32x4 bgv = *(const f32x4*)(bgate + j * 16 + lg * 4);
#pragma unroll
            for (int r = 0; r < 4; ++r) {
                float e = __expf(aG[j][r] + bgv[r]);
                aG[j][r] = e;
                den += e;
            }
        }
        den += __shfl_xor(den, 16);
        den += __shfl_xor(den, 32);
        float inv = 1.0f / den;
        if (l15 >= nvalid) inv = 0.f;   // dead lanes contribute zero

        // ---- state pass: aS[j] = Wlin-block-j x x^T
        f32x4 aS[8];
#pragma unroll
        for (int j = 0; j < 8; ++j) aS[j] = (f32x4)0.f;
#pragma unroll
        for (int kk = 0; kk < 4; ++kk) {
#pragma unroll
            for (int j = 0; j < 8; ++j) {
                const int byte = ((16 * j + l15) * 256 + kk * 64 + lg * 16)
                                 ^ ((l15 & 7) << 4);
                bf16x8 wf = *(const bf16x8*)((const char*)WL + byte);
                aS[j] = __builtin_amdgcn_mfma_f32_16x16x32_bf16(wf, xf[kk], aS[j], 0, 0, 0);
            }
        }

        // ---- gating (fully in-lane)
#pragma unroll
        for (int j = 0; j < 8; ++j) {
            f32x4 blv = *(const f32x4*)(blin + j * 16 + lg * 4);
#pragma unroll
            for (int r = 0; r < 4; ++r)
                aS[j][r] = (aS[j][r] + blv[r]) * aG[j][r] * inv;
        }

        // ---- segmented accumulation (sorted batch)
        const int bt = batch[node];
        const int gf = __shfl(bt, 0);
        const int gl = __shfl(bt, nvalid - 1);
        if (gf == gl) {
            if (gf != gcur) { flush(gcur); gcur = gf; }
#pragma unroll
            for (int j = 0; j < 8; ++j) racc[j] += aS[j];
        } else {
            for (int g = gf; g <= gl; ++g) {
                if (g != gcur) { flush(gcur); gcur = g; }
#pragma unroll
                for (int j = 0; j < 8; ++j)
#pragma unroll
                    for (int r = 0; r < 4; ++r)
                        racc[j][r] += (bt == g) ? aS[j][r] : 0.f;
            }
        }
    }
    flush(gcur);
}

// ---------------------------------------------------------------------------
// Kernel 2: mean = sums/count, out = mean @ Wf^T + bf
// ---------------------------------------------------------------------------
__global__ __launch_bounds__(128) void final_mm(
    const float* __restrict__ sums, const int* __restrict__ off,
    const float* __restrict__ Wf, const float* __restrict__ bf,
    float* __restrict__ out)
{
    const int g = blockIdx.x, c = threadIdx.x;
    __shared__ float m[128];
    const int cnt = off[g + 1] - off[g];
    const float invC = 1.0f / (float)(cnt > 0 ? cnt : 1);
    m[c] = sums[g * 128 + c] * invC;
    __syncthreads();
    float acc = bf[c];
    const f32x4* wr = (const f32x4*)(Wf + (size_t)c * 128);
#pragma unroll
    for (int k = 0; k < 32; ++k) {
        f32x4 wv = wr[k];
        acc += m[4 * k] * wv.x + m[4 * k + 1] * wv.y + m[4 * k + 2] * wv.z + m[4 * k + 3] * wv.w;
    }
    out[g * 128 + c] = acc;
}

extern "C" void kernel_launch(void* const* d_in, const int* in_sizes, int n_in,
                              void* d_out, int out_size, void* d_ws, size_t ws_size,
                              hipStream_t stream)
{
    const float* x     = (const float*)d_in[0];
    const int*   batch = (const int*)d_in[1];
    const float* Wlin  = (const float*)d_in[2];
    const float* blin  = (const float*)d_in[3];
    const float* Wgate = (const float*)d_in[4];
    const float* bgate = (const float*)d_in[5];
    const float* Wfin  = (const float*)d_in[6];
    const float* bfin  = (const float*)d_in[7];
    float* out  = (float*)d_out;
    float* sums = (float*)d_ws;                               // 512 KB
    int*   off  = (int*)((char*)d_ws + 512 * 1024);           // 1025 ints

    const int nNodes  = in_sizes[1];
    const int nGraphs = out_size / 128;

    // 16-node windows; 128 nodes per wave; 8 waves per 512-thr block
    const int PW = 128;
    const int nWaves = (nNodes + PW - 1) / PW;
    const int nB = (nWaves + 7) / 8;

    prep<<<2048, 256, 0, stream>>>(batch, nNodes, sums, off);
    gnn_main<<<nB, 512, 0, stream>>>(x, batch, Wlin, blin, Wgate, bgate, sums, nNodes, PW);
    final_mm<<<nGraphs, 128, 0, stream>>>(sums, off, Wfin, bfin, out);
}

// Round 9
// 134.250 us; speedup vs baseline: 5.1749x; 5.1749x over previous
//
#include <hip/hip_runtime.h>

typedef __attribute__((ext_vector_type(8))) __bf16 bf16x8;
typedef __attribute__((ext_vector_type(4))) float f32x4;

typedef __attribute__((address_space(3))) unsigned int as3u32;
typedef __attribute__((address_space(1))) const unsigned int as1u32;

__device__ __forceinline__ bf16x8 cvt8(f32x4 a, f32x4 b) {
    bf16x8 v;
    v[0] = (__bf16)a.x; v[1] = (__bf16)a.y; v[2] = (__bf16)a.z; v[3] = (__bf16)a.w;
    v[4] = (__bf16)b.x; v[5] = (__bf16)b.y; v[6] = (__bf16)b.z; v[7] = (__bf16)b.w;
    return v;
}

// ---------------------------------------------------------------------------
// Kernel 0: zero 512KB accumulator + build graph offsets from sorted batch.
// ---------------------------------------------------------------------------
__global__ void prep(const int* __restrict__ batch, int nN,
                     float* __restrict__ sums, int* __restrict__ off)
{
    const int i = blockIdx.x * blockDim.x + threadIdx.x;
    const int stride = gridDim.x * blockDim.x;
    for (int t = i; t < 1024 * 128; t += stride) sums[t] = 0.f;
    for (int t = i; t < nN; t += stride) {
        const int b  = batch[t];
        const int bp = (t == 0) ? -1 : batch[t - 1];
        for (int g = bp + 1; g <= b; ++g) off[g] = t;
        if (t == nN - 1) {
            for (int g = b + 1; g <= 1024; ++g) off[g] = nN;
        }
    }
}

// ---------------------------------------------------------------------------
// Kernel 1: 512 thr / 8 waves, 32-row tiles, ~34KB LDS -> 4 blocks/CU.
// launch_bounds(512,4): 128-reg cap, compiler lands at ~64 (R5 evidence) —
// NO spill. Wave w owns cols [16w,16w+16) of both states and gates. x staged
// f32 via global_load_lds (zero staging VGPRs), double-buffered, source-
// pre-swizzled 16B XOR, f32->bf16 at fragment read. Two raw barriers per
// tile. Per-graph column sums in registers; atomics only at boundaries.
// ---------------------------------------------------------------------------
__global__ __launch_bounds__(512, 4) void gnn_main(
    const float* __restrict__ x, const int* __restrict__ batch,
    const float* __restrict__ Wlin, const float* __restrict__ blin,
    const float* __restrict__ Wgate, const float* __restrict__ bgate,
    float* __restrict__ sums, int nN, int P)
{
    __shared__ float bufA[2][32 * 128];   // 2 x 16 KB f32, 16B-XOR swizzled
    __shared__ float PS[8][36];           // per-wave row partial sums (padded)
    __shared__ float invLds[32];          // per-row 1/sum

    const int tid  = threadIdx.x;
    const int lane = tid & 63;
    const int w    = tid >> 6;    // wave 0..7
    const int l15  = lane & 15;
    const int lg   = lane >> 4;   // 0..3

    const int R0 = blockIdx.x * P;
    if (R0 >= nN) return;
    const int R1b = min(R0 + P, nN);
    const int nt  = (R1b - R0 + 31) >> 5;

    // ---- W fragments (B operand): rows [16w,16w+16) of Wlin / Wgate
    bf16x8 bfrag[2][4];
    {
        const float* Wp0 = Wlin  + (size_t)(w * 16 + l15) * 128 + lg * 8;
        const float* Wp1 = Wgate + (size_t)(w * 16 + l15) * 128 + lg * 8;
#pragma unroll
        for (int kk = 0; kk < 4; ++kk) {
            bfrag[0][kk] = cvt8(*(const f32x4*)(Wp0 + kk * 32),
                                *(const f32x4*)(Wp0 + kk * 32 + 4));
            bfrag[1][kk] = cvt8(*(const f32x4*)(Wp1 + kk * 32),
                                *(const f32x4*)(Wp1 + kk * 32 + 4));
        }
    }
    const float bl = blin[w * 16 + l15];
    const float bg = bgate[w * 16 + l15];

    // ---- staging: LDS dest linear, global source pre-swizzled so that
    // LDS[row][b] = x[row][b ^ ((row&7)<<4)]; 2 x 16B per thread per tile
    const int srh = tid >> 5;          // row within 16-row group (0..15)
    const int sb  = (tid & 31) * 16;   // byte within 512B row
    int btn;
    auto STAGE = [&](int bsel, int base) {
#pragma unroll
        for (int i = 0; i < 2; ++i) {
            const int row = i * 16 + srh;
            const int nd  = base + row;
            const int ndc = nd < nN ? nd : nN - 1;
            const int bsw = sb ^ ((row & 7) << 4);
            const float* src = x + (size_t)ndc * 128 + (bsw >> 2);
            char* dst = (char*)&bufA[bsel][0] + i * 8192 + tid * 16;
            __builtin_amdgcn_global_load_lds((as1u32*)src, (as3u32*)dst, 16, 0, 0);
        }
        const int bi = base + lane;
        btn = (bi < nN) ? batch[bi] : -1;
    };

    float racc = 0.f;
    int   gcur = batch[R0];
    auto flush = [&](int g) {
        float v = racc;
        v += __shfl_xor(v, 16);
        v += __shfl_xor(v, 32);
        if (lg == 0) atomicAdd(sums + (size_t)g * 128 + w * 16 + l15, v);
        racc = 0.f;
    };

    // ---- prologue
    STAGE(0, R0);
    int bt = btn;
    asm volatile("s_waitcnt vmcnt(0)\n\ts_barrier" ::: "memory");

    for (int t = 0; t < nt; ++t) {
        const int base = R0 + (t << 5);
        const bool more = (t + 1 < nt);
        if (more) STAGE((t + 1) & 1, base + 32);   // in flight through GEMMs

        // ---- fused dual GEMM from f32 LDS tile (convert per fragment)
        f32x4 accS[2], accG[2];
#pragma unroll
        for (int r16 = 0; r16 < 2; ++r16) { accS[r16] = (f32x4)0.f; accG[r16] = (f32x4)0.f; }
        const char* bc = (const char*)&bufA[t & 1][0];
#pragma unroll
        for (int kk = 0; kk < 4; ++kk) {
#pragma unroll
            for (int r16 = 0; r16 < 2; ++r16) {
                const int row = r16 * 16 + l15;
                const int sw  = (row & 7) << 4;
                const int byt = row * 512 + kk * 128 + lg * 32;
                f32x4 u0 = *(const f32x4*)(bc + ((byt) ^ sw));
                f32x4 u1 = *(const f32x4*)(bc + ((byt + 16) ^ sw));
                bf16x8 af = cvt8(u0, u1);
                accS[r16] = __builtin_amdgcn_mfma_f32_16x16x32_bf16(af, bfrag[0][kk], accS[r16], 0, 0, 0);
                accG[r16] = __builtin_amdgcn_mfma_f32_16x16x32_bf16(af, bfrag[1][kk], accG[r16], 0, 0, 0);
            }
        }

        // ---- exp + per-wave row partials (reduce over l15) -> PS
#pragma unroll
        for (int r16 = 0; r16 < 2; ++r16) {
            f32x4 p;
#pragma unroll
            for (int r = 0; r < 4; ++r) {
                float e = __expf(accG[r16][r] + bg);
                accG[r16][r] = e;
                p[r] = e;
            }
#pragma unroll
            for (int d = 1; d <= 8; d <<= 1) {
#pragma unroll
                for (int r = 0; r < 4; ++r) p[r] += __shfl_xor(p[r], d);
            }
            if (l15 == 0) *(f32x4*)&PS[w][r16 * 16 + lg * 4] = p;
        }
        asm volatile("s_waitcnt lgkmcnt(0)\n\ts_barrier" ::: "memory");  // B1

        // ---- stage 2: total row sums (wave w -> rows [4w,4w+4))
        {
            const int p   = lane & 7;            // partial index over 8 waves
            const int rw  = w * 4 + (lane >> 4); // this lane's row
            float v = PS[p][rw];
            v += __shfl_xor(v, 1);
            v += __shfl_xor(v, 2);
            v += __shfl_xor(v, 4);
            if ((lane & 15) == 0) invLds[rw] = 1.0f / v;
        }
        // B2: invLds visible AND next f32 tile fully landed in LDS
        asm volatile("s_waitcnt vmcnt(0) lgkmcnt(0)\n\ts_barrier" ::: "memory");

        // ---- gating
#pragma unroll
        for (int r16 = 0; r16 < 2; ++r16) {
            f32x4 iv = *(const f32x4*)&invLds[r16 * 16 + lg * 4];
#pragma unroll
            for (int r = 0; r < 4; ++r)
                accS[r16][r] = (accS[r16][r] + bl) * accG[r16][r] * iv[r];
        }

        // ---- segmented per-graph accumulation (rows base..base+31, sorted)
        const int nvalid = min(32, nN - base);
        const int gf = __shfl(bt, 0);
        const int gl = __shfl(bt, nvalid - 1);
        if (nvalid == 32 && gf == gl) {
            if (gf != gcur) { flush(gcur); gcur = gf; }
            float ts = 0.f;
#pragma unroll
            for (int r16 = 0; r16 < 2; ++r16)
#pragma unroll
                for (int r = 0; r < 4; ++r) ts += accS[r16][r];
            racc += ts;
        } else {
            for (int g = gf; g <= gl; ++g) {
                float cs = 0.f;
#pragma unroll
                for (int r16 = 0; r16 < 2; ++r16)
#pragma unroll
                    for (int r = 0; r < 4; ++r) {
                        const int bid = __shfl(bt, r16 * 16 + lg * 4 + r);
                        cs += (bid == g) ? accS[r16][r] : 0.f;
                    }
                if (g == gcur) racc += cs;
                else { flush(gcur); gcur = g; racc = cs; }
            }
        }
        bt = btn;
    }
    flush(gcur);
}

// ---------------------------------------------------------------------------
// Kernel 2: mean = sums/count, out = mean @ Wf^T + bf
// ---------------------------------------------------------------------------
__global__ __launch_bounds__(128) void final_mm(
    const float* __restrict__ sums, const int* __restrict__ off,
    const float* __restrict__ Wf, const float* __restrict__ bf,
    float* __restrict__ out)
{
    const int g = blockIdx.x, c = threadIdx.x;
    __shared__ float m[128];
    const int cnt = off[g + 1] - off[g];
    const float invC = 1.0f / (float)(cnt > 0 ? cnt : 1);
    m[c] = sums[g * 128 + c] * invC;
    __syncthreads();
    float acc = bf[c];
    const f32x4* wr = (const f32x4*)(Wf + (size_t)c * 128);
#pragma unroll
    for (int k = 0; k < 32; ++k) {
        f32x4 wv = wr[k];
        acc += m[4 * k] * wv.x + m[4 * k + 1] * wv.y + m[4 * k + 2] * wv.z + m[4 * k + 3] * wv.w;
    }
    out[g * 128 + c] = acc;
}

extern "C" void kernel_launch(void* const* d_in, const int* in_sizes, int n_in,
                              void* d_out, int out_size, void* d_ws, size_t ws_size,
                              hipStream_t stream)
{
    const float* x     = (const float*)d_in[0];
    const int*   batch = (const int*)d_in[1];
    const float* Wlin  = (const float*)d_in[2];
    const float* blin  = (const float*)d_in[3];
    const float* Wgate = (const float*)d_in[4];
    const float* bgate = (const float*)d_in[5];
    const float* Wfin  = (const float*)d_in[6];
    const float* bfin  = (const float*)d_in[7];
    float* out  = (float*)d_out;
    float* sums = (float*)d_ws;                               // 512 KB
    int*   off  = (int*)((char*)d_ws + 512 * 1024);           // 1025 ints

    const int nNodes  = in_sizes[1];
    const int nGraphs = out_size / 128;

    // ~977 blocks (4 resident/CU target), contiguous ranges, P multiple of 32
    const int P  = ((((nNodes + 1023) / 1024) + 31) & ~31);
    const int nB = (nNodes + P - 1) / P;

    prep<<<2048, 256, 0, stream>>>(batch, nNodes, sums, off);
    gnn_main<<<nB, 512, 0, stream>>>(x, batch, Wlin, blin, Wgate, bgate, sums, nNodes, P);
    final_mm<<<nGraphs, 128, 0, stream>>>(sums, off, Wfin, bfin, out);
}

// Round 10
// 84.388 us; speedup vs baseline: 8.2325x; 1.5909x over previous
//
#include <hip/hip_runtime.h>

typedef __attribute__((ext_vector_type(8))) __bf16 bf16x8;
typedef __attribute__((ext_vector_type(4))) float f32x4;

__device__ __forceinline__ bf16x8 cvt8(f32x4 a, f32x4 b) {
    bf16x8 v;
    v[0] = (__bf16)a.x; v[1] = (__bf16)a.y; v[2] = (__bf16)a.z; v[3] = (__bf16)a.w;
    v[4] = (__bf16)b.x; v[5] = (__bf16)b.y; v[6] = (__bf16)b.z; v[7] = (__bf16)b.w;
    return v;
}

// VALU-pipe cross-lane add via DPP (replaces ds_swizzle-based __shfl_xor)
template <int CTRL>
__device__ __forceinline__ float dpp_addf(float v) {
    union { float f; int i; } s, r;
    s.f = v;
    r.i = __builtin_amdgcn_update_dpp(0, s.i, CTRL, 0xF, 0xF, true);
    return v + r.f;
}

// ---------------------------------------------------------------------------
// Kernel 0: zero 512KB accumulator + build graph offsets from sorted batch.
// ---------------------------------------------------------------------------
__global__ void prep(const int* __restrict__ batch, int nN,
                     float* __restrict__ sums, int* __restrict__ off)
{
    const int i = blockIdx.x * blockDim.x + threadIdx.x;
    const int stride = gridDim.x * blockDim.x;
    for (int t = i; t < 1024 * 128; t += stride) sums[t] = 0.f;
    for (int t = i; t < nN; t += stride) {
        const int b  = batch[t];
        const int bp = (t == 0) ? -1 : batch[t - 1];
        for (int g = bp + 1; g <= b; ++g) off[g] = t;
        if (t == nN - 1) {
            for (int g = b + 1; g <= 1024; ++g) off[g] = nN;
        }
    }
}

// ---------------------------------------------------------------------------
// Kernel 1: 512 thr / 8 waves, 32-row bf16 tiles (2x8KB, XOR-swizzled),
// register-staged with cvt at stage time (one ds_write_b128/thread/tile).
// Wave w owns cols [16w,16w+16) of both states and gates (W frags in regs).
// Softmax cross-lane reduces run on the VALU via DPP. Two lgkm-only barriers
// per tile; no vmcnt drains (compiler counts the reg-staged loads exactly).
// Per-graph column sums in registers; atomics only at graph boundaries.
// ---------------------------------------------------------------------------
__global__ __launch_bounds__(512, 2) void gnn_main(
    const float* __restrict__ x, const int* __restrict__ batch,
    const float* __restrict__ Wlin, const float* __restrict__ blin,
    const float* __restrict__ Wgate, const float* __restrict__ bgate,
    float* __restrict__ sums, int nN, int P)
{
    __shared__ __bf16 buf[2][32 * 128];   // 2 x 8 KB bf16, 16B-XOR swizzled
    __shared__ float  PS[8][36];          // per-wave row partial sums (padded)
    __shared__ float  invLds[32];         // per-row 1/sum

    const int tid  = threadIdx.x;
    const int lane = tid & 63;
    const int w    = tid >> 6;    // wave 0..7
    const int l15  = lane & 15;
    const int lg   = lane >> 4;   // 0..3

    const int R0 = blockIdx.x * P;
    if (R0 >= nN) return;
    const int R1b = min(R0 + P, nN);
    const int nt  = (R1b - R0 + 31) >> 5;

    // ---- W fragments (B operand): rows [16w,16w+16) of Wlin / Wgate
    bf16x8 bfrag[2][4];
    {
        const float* Wp0 = Wlin  + (size_t)(w * 16 + l15) * 128 + lg * 8;
        const float* Wp1 = Wgate + (size_t)(w * 16 + l15) * 128 + lg * 8;
#pragma unroll
        for (int kk = 0; kk < 4; ++kk) {
            bfrag[0][kk] = cvt8(*(const f32x4*)(Wp0 + kk * 32),
                                *(const f32x4*)(Wp0 + kk * 32 + 4));
            bfrag[1][kk] = cvt8(*(const f32x4*)(Wp1 + kk * 32),
                                *(const f32x4*)(Wp1 + kk * 32 + 4));
        }
    }
    const float bl = blin[w * 16 + l15];
    const float bg = bgate[w * 16 + l15];

    // ---- staging: thread covers x[base + (tid>>4)][(tid&15)*8 .. +7]
    const int srow = tid >> 4;         // 0..31
    const int skg  = tid & 15;         // 8-elem group
    f32x4 lv0, lv1;
    int   btn;
    auto stage_load = [&](int base) {
        const int nd = base + srow;
        const float* p = x + (size_t)(nd < nN ? nd : nN - 1) * 128 + skg * 8;
        lv0 = *(const f32x4*)p;
        lv1 = *(const f32x4*)(p + 4);
        const int bi = base + lane;
        btn = (bi < nN) ? batch[bi] : -1;
    };
    auto stage_write = [&](int bsel) {   // compiler inserts counted vmcnt here
        const int byte = (srow * 256 + skg * 16) ^ ((srow & 7) << 4);
        *(bf16x8*)((char*)&buf[bsel][0] + byte) = cvt8(lv0, lv1);
    };

    float racc = 0.f;
    int   gcur = batch[R0];
    auto flush = [&](int g) {
        float v = racc;
        v += __shfl_xor(v, 16);
        v += __shfl_xor(v, 32);
        if (lg == 0) atomicAdd(sums + (size_t)g * 128 + w * 16 + l15, v);
        racc = 0.f;
    };

    // ---- prologue: tile 0 staged
    stage_load(R0);
    stage_write(0);
    int bt = btn;
    asm volatile("s_waitcnt lgkmcnt(0)\n\ts_barrier" ::: "memory");

    for (int t = 0; t < nt; ++t) {
        const int base = R0 + (t << 5);
        const bool more = (t + 1 < nt);
        if (more) stage_load(base + 32);   // loads in flight through GEMMs

        // ---- fused dual GEMM from bf16 LDS tile (no cvt in hot loop)
        f32x4 accS[2], accG[2];
#pragma unroll
        for (int r16 = 0; r16 < 2; ++r16) { accS[r16] = (f32x4)0.f; accG[r16] = (f32x4)0.f; }
        const char* bc = (const char*)&buf[t & 1][0];
#pragma unroll
        for (int kk = 0; kk < 4; ++kk) {
#pragma unroll
            for (int r16 = 0; r16 < 2; ++r16) {
                const int row  = r16 * 16 + l15;
                const int byte = (row * 256 + kk * 64 + lg * 16) ^ ((l15 & 7) << 4);
                bf16x8 af = *(const bf16x8*)(bc + byte);
                accS[r16] = __builtin_amdgcn_mfma_f32_16x16x32_bf16(af, bfrag[0][kk], accS[r16], 0, 0, 0);
                accG[r16] = __builtin_amdgcn_mfma_f32_16x16x32_bf16(af, bfrag[1][kk], accG[r16], 0, 0, 0);
            }
        }

        // ---- exp + 16-lane row sums on the VALU (DPP ror 8/4/2/1)
#pragma unroll
        for (int r16 = 0; r16 < 2; ++r16) {
            f32x4 pv;
#pragma unroll
            for (int r = 0; r < 4; ++r) {
                float e = __expf(accG[r16][r] + bg);
                accG[r16][r] = e;
                float s = e;
                s = dpp_addf<0x128>(s);   // row_ror:8
                s = dpp_addf<0x124>(s);   // row_ror:4
                s = dpp_addf<0x122>(s);   // row_ror:2
                s = dpp_addf<0x121>(s);   // row_ror:1
                pv[r] = s;
            }
            if (l15 == 0) *(f32x4*)&PS[w][r16 * 16 + lg * 4] = pv;
        }

        if (more) stage_write((t + 1) & 1);   // write-late (T14), pre-B1
        asm volatile("s_waitcnt lgkmcnt(0)\n\ts_barrier" ::: "memory");  // B1

        // ---- stage 2: rows [4w,4w+4), 8 partials each (x2 duplicated)
        {
            const int rw = w * 4 + (lane >> 4);
            float v = PS[lane & 7][rw];
            v = dpp_addf<0x124>(v);   // ror:4 == xor:4 under 8-dup
            v = dpp_addf<0x4E>(v);    // quad_perm(2,3,0,1) == xor:2
            v = dpp_addf<0xB1>(v);    // quad_perm(1,0,3,2) == xor:1
            if ((lane & 15) == 0) invLds[rw] = 1.0f / v;
        }
        asm volatile("s_waitcnt lgkmcnt(0)\n\ts_barrier" ::: "memory");  // B2

        // ---- gating
#pragma unroll
        for (int r16 = 0; r16 < 2; ++r16) {
            f32x4 iv = *(const f32x4*)&invLds[r16 * 16 + lg * 4];
#pragma unroll
            for (int r = 0; r < 4; ++r)
                accS[r16][r] = (accS[r16][r] + bl) * accG[r16][r] * iv[r];
        }

        // ---- segmented per-graph accumulation (rows base..base+31, sorted)
        const int nvalid = min(32, nN - base);
        const int gf = __builtin_amdgcn_readlane(bt, 0);
        const int gl = __builtin_amdgcn_readlane(bt, nvalid - 1);
        if (nvalid == 32 && gf == gl) {
            if (gf != gcur) { flush(gcur); gcur = gf; }
            float ts = 0.f;
#pragma unroll
            for (int r16 = 0; r16 < 2; ++r16)
#pragma unroll
                for (int r = 0; r < 4; ++r) ts += accS[r16][r];
            racc += ts;
        } else {
            for (int g = gf; g <= gl; ++g) {
                float cs = 0.f;
#pragma unroll
                for (int r16 = 0; r16 < 2; ++r16)
#pragma unroll
                    for (int r = 0; r < 4; ++r) {
                        const int bid = __shfl(bt, r16 * 16 + lg * 4 + r);
                        cs += (bid == g) ? accS[r16][r] : 0.f;
                    }
                if (g == gcur) racc += cs;
                else { flush(gcur); gcur = g; racc = cs; }
            }
        }
        bt = btn;
    }
    flush(gcur);
}

// ---------------------------------------------------------------------------
// Kernel 2: mean = sums/count, out = mean @ Wf^T + bf
// ---------------------------------------------------------------------------
__global__ __launch_bounds__(128) void final_mm(
    const float* __restrict__ sums, const int* __restrict__ off,
    const float* __restrict__ Wf, const float* __restrict__ bf,
    float* __restrict__ out)
{
    const int g = blockIdx.x, c = threadIdx.x;
    __shared__ float m[128];
    const int cnt = off[g + 1] - off[g];
    const float invC = 1.0f / (float)(cnt > 0 ? cnt : 1);
    m[c] = sums[g * 128 + c] * invC;
    __syncthreads();
    float acc = bf[c];
    const f32x4* wr = (const f32x4*)(Wf + (size_t)c * 128);
#pragma unroll
    for (int k = 0; k < 32; ++k) {
        f32x4 wv = wr[k];
        acc += m[4 * k] * wv.x + m[4 * k + 1] * wv.y + m[4 * k + 2] * wv.z + m[4 * k + 3] * wv.w;
    }
    out[g * 128 + c] = acc;
}

extern "C" void kernel_launch(void* const* d_in, const int* in_sizes, int n_in,
                              void* d_out, int out_size, void* d_ws, size_t ws_size,
                              hipStream_t stream)
{
    const float* x     = (const float*)d_in[0];
    const int*   batch = (const int*)d_in[1];
    const float* Wlin  = (const float*)d_in[2];
    const float* blin  = (const float*)d_in[3];
    const float* Wgate = (const float*)d_in[4];
    const float* bgate = (const float*)d_in[5];
    const float* Wfin  = (const float*)d_in[6];
    const float* bfin  = (const float*)d_in[7];
    float* out  = (float*)d_out;
    float* sums = (float*)d_ws;                               // 512 KB
    int*   off  = (int*)((char*)d_ws + 512 * 1024);           // 1025 ints

    const int nNodes  = in_sizes[1];
    const int nGraphs = out_size / 128;

    // ~977 blocks, contiguous ranges, P multiple of 32
    const int P  = ((((nNodes + 1023) / 1024) + 31) & ~31);
    const int nB = (nNodes + P - 1) / P;

    prep<<<2048, 256, 0, stream>>>(batch, nNodes, sums, off);
    gnn_main<<<nB, 512, 0, stream>>>(x, batch, Wlin, blin, Wgate, bgate, sums, nNodes, P);
    final_mm<<<nGraphs, 128, 0, stream>>>(sums, off, Wfin, bfin, out);
}